// Round 8
// baseline (205.630 us; speedup 1.0000x reference)
//
#include <hip/hip_runtime.h>
#include <hip/hip_bf16.h>

#define B_    128
#define T_    1000
#define D_    1024
#define H_    256
#define TCROP 100
#define CHUNK 25
#define NCHK  40           // T_/CHUNK
#define CSKIP 4            // TCROP/CHUNK exact
#define NOUTC 36           // NCHK - CSKIP
#define BM    125          // valid rows per gemm block (chunk-aligned)

typedef __attribute__((ext_vector_type(8))) short bfrag8;   // 8 x bf16
typedef __attribute__((ext_vector_type(4))) float f32x4;
typedef unsigned long long ull;

__device__ __forceinline__ float bf2f(unsigned short u) {
    union { unsigned int u; float f; } v; v.u = ((unsigned int)u) << 16;
    return v.f;
}
__device__ __forceinline__ unsigned short f2bf(float f) {
    union { float f; unsigned int u; } v; v.f = f;
    unsigned int u = v.u;
    u += 0x7FFFu + ((u >> 16) & 1u);   // RNE
    return (unsigned short)(u >> 16);
}
// two f32 -> packed 2x bf16 (RNE) via v_cvt_pk_bf16_f32
__device__ __forceinline__ unsigned int cvtpk2(float lo, float hi) {
    union { __hip_bfloat162 h; unsigned int u; } v;
    v.h = __float22bfloat162_rn(make_float2(lo, hi));
    return v.u;
}

// ---------------------------------------------------------------------------
// Kernel 0: W f32 [H][D] -> fragment-ordered bf16:
//   Bfr[((c16*16 + hb)*64 + lane)*8 + e] = bf16(W[hb*16 + (lane&15)]
//                                               [c16*32 + (lane>>4)*8 + e])
// so a wave's B-frag read is one coalesced 1KB global_load_dwordx4 (L2-hot).
// ---------------------------------------------------------------------------
__global__ __launch_bounds__(256) void wconv_kernel(
        const float* __restrict__ W, unsigned short* __restrict__ Bfr) {
    const int g    = blockIdx.x * 256 + threadIdx.x;   // 0..32767
    const int lane = g & 63;
    const int grp  = g >> 6;            // 0..511
    const int c16  = grp >> 4;          // 0..31
    const int hb   = grp & 15;          // 0..15
    const int row  = hb * 16 + (lane & 15);
    const int col  = c16 * 32 + (lane >> 4) * 8;
    const float* src = W + (size_t)row * D_ + col;
    float4 f0 = *(const float4*)src;
    float4 f1 = *(const float4*)(src + 4);
    union { bfrag8 v; unsigned int u[4]; } r;
    r.u[0] = cvtpk2(f0.x, f0.y);
    r.u[1] = cvtpk2(f0.z, f0.w);
    r.u[2] = cvtpk2(f1.x, f1.y);
    r.u[3] = cvtpk2(f1.z, f1.w);
    *(bfrag8*)(Bfr + (size_t)g * 8) = r.v;
}

// ---------------------------------------------------------------------------
// Kernel 1: block (c,b) computes Wx rows t=[c*125, c*125+125) of batch b.
// A: f32 direct-to-LDS via global_load_lds, DOUBLE-buffered (2x32KB);
//    stage(nxt) issued at iter top, awaited by end-of-iter __syncthreads
//    -> loads in flight during the whole MFMA phase; 1 barrier/K-step.
//    16B-granule XOR swizzle j ^ (((r&7)<<1)|((r>>3)&1)), source-preswizzled.
// B: fragment-ordered bf16 from L2 (no LDS), coalesced b128 per frag.
// f32->bf16 for A at fragment read via v_cvt_pk_bf16_f32.
// Epilogue: acc -> LDS C-tile (bf16), waves 0-3 EMA->F, waves 4-7 Wx stores.
// ---------------------------------------------------------------------------
__global__ __launch_bounds__(512) void gemm_ema_kernel(
        const float* __restrict__ x, const unsigned short* __restrict__ Bfr,
        const float* __restrict__ alpha,
        unsigned short* __restrict__ Wx, float* __restrict__ F) {
    __shared__ unsigned int smem4[16384];     // 64 KB
    float* As = (float*)smem4;                // 2 x [128 rows][64 f32]

    const int tid  = threadIdx.x;
    const int lane = tid & 63;
    const int wave = tid >> 6;
    const int wr   = wave >> 2;          // 0..1
    const int wc   = wave & 3;           // 0..3
    const int c    = blockIdx.x;         // 0..7
    const int b    = blockIdx.y;
    const int m0   = b * T_ + c * BM;

    f32x4 acc[4][4];
#pragma unroll
    for (int m = 0; m < 4; ++m)
#pragma unroll
        for (int n = 0; n < 4; ++n) acc[m][n] = (f32x4){0.f, 0.f, 0.f, 0.f};

    const int rr  = lane & 15;
    const int kh  = lane >> 4;                      // 0..3
    const int swz = ((rr & 7) << 1) | (rr >> 3);    // 4-bit bijection per 16 rows

    // ---- stage addressing (it-independent): q=0..3, li=q*512+tid ----
    const float* asrc[4];
    int sdst[4];
#pragma unroll
    for (int q = 0; q < 4; ++q) {
        const int li = q * 512 + tid;
        const int r  = li >> 4;                     // 0..127
        const int j  = li & 15;
        const int rs = (r < BM) ? r : (BM - 1);     // clamp pad rows
        const int js = j ^ (((r & 7) << 1) | ((r >> 3) & 1));
        asrc[q] = x + (size_t)(m0 + rs) * D_ + js * 4;
        sdst[q] = li * 4;                           // float index (16B granule)
    }
    // frag row offsets (floats)
    int rowoff[4];
#pragma unroll
    for (int m = 0; m < 4; ++m) rowoff[m] = (wr * 64 + m * 16 + rr) * 64;

    const unsigned short* bbase = Bfr + ((size_t)(wc * 4) << 9) + lane * 8;

    // ---- prologue: stage K-tile 0 into buf 0 ----
#pragma unroll
    for (int q = 0; q < 4; ++q)
        __builtin_amdgcn_global_load_lds(
            (const __attribute__((address_space(1))) void*)asrc[q],
            (__attribute__((address_space(3))) void*)&As[sdst[q]], 16, 0, 0);
    __syncthreads();

    for (int it = 0; it < 16; ++it) {
        const int cur = it & 1, nxt = cur ^ 1;
        // ---- issue next-tile A stage (in flight during MFMA below) ----
        if (it < 15) {
            const int ktn = (it + 1) * 64;
#pragma unroll
            for (int q = 0; q < 4; ++q)
                __builtin_amdgcn_global_load_lds(
                    (const __attribute__((address_space(1))) void*)(asrc[q] + ktn),
                    (__attribute__((address_space(3))) void*)
                        &As[nxt * 8192 + sdst[q]], 16, 0, 0);
        }
        // ---- compute from buf cur ----
#pragma unroll
        for (int kk = 0; kk < 2; ++kk) {
            // B frags first (L2 latency > LDS)
            bfrag8 bfr[4];
            const size_t boff = (size_t)(it * 2 + kk) * 8192;
#pragma unroll
            for (int n = 0; n < 4; ++n)
                bfr[n] = *(const bfrag8*)(bbase + boff + (size_t)n * 512);
            const int gl = (2 * (kk * 4 + kh)) ^ swz;
            bfrag8 af[4];
#pragma unroll
            for (int m = 0; m < 4; ++m) {
                const float* pa = As + cur * 8192 + rowoff[m];
                float4 lo = *(const float4*)(pa + gl * 4);
                float4 hi = *(const float4*)(pa + (gl ^ 1) * 4);
                union { bfrag8 v; unsigned int u[4]; } t;
                t.u[0] = cvtpk2(lo.x, lo.y);
                t.u[1] = cvtpk2(lo.z, lo.w);
                t.u[2] = cvtpk2(hi.x, hi.y);
                t.u[3] = cvtpk2(hi.z, hi.w);
                af[m] = t.v;
            }
#pragma unroll
            for (int m = 0; m < 4; ++m)
#pragma unroll
                for (int n = 0; n < 4; ++n)
                    acc[m][n] = __builtin_amdgcn_mfma_f32_16x16x32_bf16(
                        af[m], bfr[n], acc[m][n], 0, 0, 0);
        }
        __syncthreads();    // drains stage(nxt) vmcnt + barrier: buf swap safe
    }

    // ---- acc -> LDS C-tile [125][256] bf16, col swizzle as round 7 ----
    unsigned short* ct = (unsigned short*)smem4;
    const int cl = lane & 15, rg = lane >> 4;
#pragma unroll
    for (int m = 0; m < 4; ++m)
#pragma unroll
        for (int n = 0; n < 4; ++n)
#pragma unroll
            for (int j = 0; j < 4; ++j) {
                const int row = wr * 64 + m * 16 + rg * 4 + j;
                if (row < BM) {
                    const int col = wc * 64 + n * 16 + cl;
                    ct[row * 256 + (col ^ (((row >> 2) & 3) << 4))] =
                        f2bf(acc[m][n][j]);
                }
            }
    __syncthreads();

    if (tid < 256) {
        // ---- waves 0-3: chunk-local EMA, snapshot every 25 rows -> F ----
        const int h = tid;
        const float AMIN = 0.81873075307798182f, AMAX = 0.96078943915232320f;
        const float a  = fminf(fmaxf(alpha[h], AMIN), AMAX);
        const float om = 1.0f - a;
        float ut = 0.f;
        const size_t fbase = ((size_t)b * NCHK + c * 5) * H_ + h;
#pragma unroll 5
        for (int r = 0; r < BM; ++r) {
            ut = a * ut + om * bf2f(ct[r * 256 + (h ^ (((r >> 2) & 3) << 4))]);
            if ((r % 25) == 24) {
                F[fbase + (size_t)(r / 25) * H_] = ut;
                ut = 0.f;
            }
        }
    } else {
        // ---- waves 4-7: coalesced Wx stores from LDS (t>=100 only) ----
        const int nrows = (c == 0) ? (BM - TCROP) : BM;
        const int rbase = (c == 0) ? TCROP : 0;
        const int total = nrows * 32;             // 32 b128-slots per row
        for (int li = tid - 256; li < total; li += 256) {
            const int r  = rbase + (li >> 5);
            const int cg = (li & 31) * 8;
            const int scg = cg ^ (((r >> 2) & 3) << 4);
            bfrag8 v = *(const bfrag8*)&ct[r * 256 + scg];
            const int t = c * BM + r;
            *(bfrag8*)&Wx[((size_t)b * T_ + t) * H_ + cg] = v;
        }
    }
}

// ---------------------------------------------------------------------------
// Kernel 2 (scanC): seed-chain from F (a^25 powers, F L2-hot), then seeded
// softmax accumulation. Wave w owns chunk c = 4 + bx*4 + w.
// ---------------------------------------------------------------------------
__global__ __launch_bounds__(256) void scanC_kernel(
        const unsigned short* __restrict__ Wx, const float* __restrict__ alpha,
        const float* __restrict__ F, float* __restrict__ P) {
    const int wave = threadIdx.x >> 6;
    const int lane = threadIdx.x & 63;
    const int c = CSKIP + blockIdx.x * 4 + wave;   // 4..39
    const int b = blockIdx.y;
    const int h4 = lane * 4;

    const float AMIN = 0.81873075307798182f, AMAX = 0.96078943915232320f;
    float4 al = *(const float4*)(alpha + h4);
    float a[4]  = {fminf(fmaxf(al.x, AMIN), AMAX), fminf(fmaxf(al.y, AMIN), AMAX),
                   fminf(fmaxf(al.z, AMIN), AMAX), fminf(fmaxf(al.w, AMIN), AMAX)};
    float om[4] = {1.f - a[0], 1.f - a[1], 1.f - a[2], 1.f - a[3]};

    float aL[4] = {__powf(a[0], (float)CHUNK), __powf(a[1], (float)CHUNK),
                   __powf(a[2], (float)CHUNK), __powf(a[3], (float)CHUNK)};
    float S[4] = {0.f, 0.f, 0.f, 0.f};
    for (int j = 0; j < c; ++j) {
        float4 f = *(const float4*)(F + ((size_t)b * NCHK + j) * H_ + h4);
        S[0] = aL[0] * S[0] + f.x;
        S[1] = aL[1] * S[1] + f.y;
        S[2] = aL[2] * S[2] + f.z;
        S[3] = aL[3] * S[3] + f.w;
    }

    float ut[4]   = {S[0], S[1], S[2], S[3]};
    float acc4[4] = {0.f, 0.f, 0.f, 0.f};
    const unsigned short* base = Wx + ((size_t)b * T_ + c * CHUNK) * H_ + h4;

#pragma unroll
    for (int bb = 0; bb < CHUNK; bb += 5) {
        float e[5][4], sl[5];
#pragma unroll
        for (int q = 0; q < 5; ++q) {
            ull wv = *(const ull*)(base + (size_t)(bb + q) * H_);
            ut[0] = a[0] * ut[0] + om[0] * bf2f((unsigned short)wv);
            ut[1] = a[1] * ut[1] + om[1] * bf2f((unsigned short)(wv >> 16));
            ut[2] = a[2] * ut[2] + om[2] * bf2f((unsigned short)(wv >> 32));
            ut[3] = a[3] * ut[3] + om[3] * bf2f((unsigned short)(wv >> 48));
            e[q][0] = __expf(ut[0]);   // |ut| small: no overflow, skip max-sub
            e[q][1] = __expf(ut[1]);
            e[q][2] = __expf(ut[2]);
            e[q][3] = __expf(ut[3]);
            sl[q] = (e[q][0] + e[q][1]) + (e[q][2] + e[q][3]);
        }
#pragma unroll
        for (int dd = 1; dd < 64; dd <<= 1) {
            sl[0] += __shfl_xor(sl[0], dd);
            sl[1] += __shfl_xor(sl[1], dd);
            sl[2] += __shfl_xor(sl[2], dd);
            sl[3] += __shfl_xor(sl[3], dd);
            sl[4] += __shfl_xor(sl[4], dd);
        }
#pragma unroll
        for (int q = 0; q < 5; ++q) {
            const float rcp = 1.0f / sl[q];
            acc4[0] += e[q][0] * rcp;
            acc4[1] += e[q][1] * rcp;
            acc4[2] += e[q][2] * rcp;
            acc4[3] += e[q][3] * rcp;
        }
    }
    float4 o; o.x = acc4[0]; o.y = acc4[1]; o.z = acc4[2]; o.w = acc4[3];
    *(float4*)(P + ((size_t)b * NOUTC + (c - CSKIP)) * H_ + h4) = o;
}

// ---------------------------------------------------------------------------
// Kernel 3: reduce chunk partials
// ---------------------------------------------------------------------------
__global__ __launch_bounds__(256) void scanD_kernel(
        const float* __restrict__ P, float* __restrict__ out) {
    const int b = blockIdx.x, h = threadIdx.x;
    float s = 0.f;
#pragma unroll 4
    for (int k = 0; k < NOUTC; ++k) s += P[((size_t)b * NOUTC + k) * H_ + h];
    out[(size_t)b * H_ + h] = s;
}

extern "C" void kernel_launch(void* const* d_in, const int* in_sizes, int n_in,
                              void* d_out, int out_size, void* d_ws, size_t ws_size,
                              hipStream_t stream) {
    const float* x     = (const float*)d_in[0];   // [B,T,D]
    const float* W     = (const float*)d_in[1];   // [H,D]
    const float* alpha = (const float*)d_in[2];   // [H]
    float* out = (float*)d_out;                   // [B,H]

    char* ws = (char*)d_ws;
    unsigned short* Bfr = (unsigned short*)ws;                        // 512 KB
    unsigned short* Wx  = (unsigned short*)(ws + ((size_t)1 << 20));  // 65.5 MB
    float* F = (float*)(ws + ((size_t)70 << 20));                     // 5.2 MB
    float* P = (float*)(ws + ((size_t)80 << 20));                     // 4.7 MB

    wconv_kernel<<<128, 256, 0, stream>>>(W, Bfr);
    gemm_ema_kernel<<<dim3(T_ / BM, B_), 512, 0, stream>>>(x, Bfr, alpha, Wx, F);
    scanC_kernel<<<dim3(NOUTC / 4, B_), 256, 0, stream>>>(Wx, alpha, F, P);
    scanD_kernel<<<B_, 256, 0, stream>>>(P, out);
}

// Round 9
// 178.364 us; speedup vs baseline: 1.1529x; 1.1529x over previous
//
#include <hip/hip_runtime.h>
#include <hip/hip_bf16.h>

#define B_    128
#define T_    1000
#define D_    1024
#define H_    256
#define TCROP 100
#define CHUNK 50
#define NCH   20            // T_/CHUNK
#define CSKIP 2             // TCROP/CHUNK (exact)

typedef __attribute__((ext_vector_type(8))) short bfrag8;   // 8 x bf16
typedef __attribute__((ext_vector_type(4))) float f32x4;
typedef unsigned long long ull;

__device__ __forceinline__ unsigned short f2bf(float f) {
    union { float f; unsigned int u; } v; v.f = f;
    unsigned int u = v.u;
    u += 0x7FFFu + ((u >> 16) & 1u);   // RNE
    return (unsigned short)(u >> 16);
}
__device__ __forceinline__ float bf2f(unsigned short u) {
    union { unsigned int u; float f; } v; v.u = ((unsigned int)u) << 16;
    return v.f;
}
// pack two f32 -> (bf16(hi)<<16)|bf16(lo), round-half-away: 2 adds + 1 v_perm
__device__ __forceinline__ unsigned int pack2(float lo, float hi) {
    union { float f; unsigned int u; } a, b; a.f = lo; b.f = hi;
    return __builtin_amdgcn_perm(b.u + 0x8000u, a.u + 0x8000u, 0x07060302u);
}
__device__ __forceinline__ bfrag8 cvt8(float4 f0, float4 f1) {
    union { bfrag8 v; unsigned int u[4]; } r;
    r.u[0] = pack2(f0.x, f0.y);
    r.u[1] = pack2(f0.z, f0.w);
    r.u[2] = pack2(f1.x, f1.y);
    r.u[3] = pack2(f1.z, f1.w);
    return r.v;
}

// ---------------------------------------------------------------------------
// Kernel 0: W f32 [H][D] -> bf16 (row-major)
// ---------------------------------------------------------------------------
__global__ __launch_bounds__(256) void wconv_kernel(
        const float* __restrict__ W, unsigned short* __restrict__ Wbf) {
    const int i = (blockIdx.x * 256 + threadIdx.x) * 8;
    float4 f0 = *(const float4*)(W + i);
    float4 f1 = *(const float4*)(W + i + 4);
    *(bfrag8*)(Wbf + i) = cvt8(f0, f1);
}

// ---------------------------------------------------------------------------
// Kernel 1: Wx = x(bf16) . W^T. BM=128, BN=256(=H), BK=64. ROUND-2 EXACT
// STRUCTURE (175 us champion): 512 thr = 8 waves (2M x 4N), single-buffer
// 48 KB LDS, 2 barriers/K-step, B gload_lds issued FIRST, A f32 reg loads
// + cvt + swizzled ds_write. Only change vs round 2: pack2 (3-op) cvt.
// ---------------------------------------------------------------------------
__global__ __launch_bounds__(512) void gemm_kernel(
        const float* __restrict__ x, const unsigned short* __restrict__ Wbf,
        unsigned short* __restrict__ Wx) {
    __shared__ unsigned short As[128 * 64];   // 16 KB  [128][64] bf16
    __shared__ unsigned short Bs[256 * 64];   // 32 KB  [256][64] bf16

    const int tid  = threadIdx.x;
    const int lane = tid & 63;
    const int wave = tid >> 6;
    const int wr   = wave >> 2;          // 0..1
    const int wc   = wave & 3;           // 0..3
    const int m0   = blockIdx.x * 128;

    f32x4 acc[4][4];
#pragma unroll
    for (int m = 0; m < 4; ++m)
#pragma unroll
        for (int n = 0; n < 4; ++n) acc[m][n] = (f32x4){0.f, 0.f, 0.f, 0.f};

    const int rr  = lane & 15;
    const int kh  = lane >> 4;           // 0..3
    const int ra0 = tid >> 3;            // A-stage row (and +64)
    const int ja  = tid & 7;             // A-stage chunk
    const int sa  = (ja ^ (ra0 & 7)) * 8;

    for (int kt = 0; kt < D_; kt += 64) {
        // ---- B stage: 4x global_load_lds, 16B/lane, source pre-swizzled ----
#pragma unroll
        for (int q = 0; q < 4; ++q) {
            const int li = q * 512 + tid;        // 0..2047
            const int r  = li >> 3;
            const int j  = li & 7;
            const int jj = j ^ (r & 7);
            const unsigned short* src = Wbf + (size_t)r * D_ + kt + jj * 8;
            unsigned short* dst = &Bs[li * 8];
            __builtin_amdgcn_global_load_lds(
                (const __attribute__((address_space(1))) void*)src,
                (__attribute__((address_space(3))) void*)dst, 16, 0, 0);
        }
        // ---- A stage: reg path, f32->bf16, write-side swizzle ----
#pragma unroll
        for (int q = 0; q < 2; ++q) {
            const int r = ra0 + q * 64;
            const float* src = x + (size_t)(m0 + r) * D_ + kt + ja * 8;
            float4 f0 = *(const float4*)src;
            float4 f1 = *(const float4*)(src + 4);
            *(bfrag8*)&As[r * 64 + sa] = cvt8(f0, f1);
        }
        __syncthreads();

        // ---- fragments + MFMA ----
#pragma unroll
        for (int kk = 0; kk < 2; ++kk) {
            const int c16 = kk * 4 + kh;
            bfrag8 af[4], bfr[4];
#pragma unroll
            for (int m = 0; m < 4; ++m) {
                const int row = wr * 64 + m * 16 + rr;
                af[m] = *(const bfrag8*)&As[row * 64 + ((c16 ^ (row & 7)) * 8)];
            }
#pragma unroll
            for (int n = 0; n < 4; ++n) {
                const int row = wc * 64 + n * 16 + rr;
                bfr[n] = *(const bfrag8*)&Bs[row * 64 + ((c16 ^ (row & 7)) * 8)];
            }
#pragma unroll
            for (int m = 0; m < 4; ++m)
#pragma unroll
                for (int n = 0; n < 4; ++n)
                    acc[m][n] = __builtin_amdgcn_mfma_f32_16x16x32_bf16(
                        af[m], bfr[n], acc[m][n], 0, 0, 0);
        }
        __syncthreads();
    }

    // ---- epilogue: bf16 store. C[row=(lane>>4)*4+j][col=lane&15] ----
    const int cl = lane & 15, rg = lane >> 4;
#pragma unroll
    for (int m = 0; m < 4; ++m)
#pragma unroll
        for (int n = 0; n < 4; ++n)
#pragma unroll
            for (int j = 0; j < 4; ++j) {
                const int row = m0 + wr * 64 + m * 16 + rg * 4 + j;
                const int col = wc * 64 + n * 16 + cl;
                Wx[(size_t)row * H_ + col] = f2bf(acc[m][n][j]);
            }
}

// ---------------------------------------------------------------------------
// Scan: chunked linear-recurrence decomposition (CHUNK=50, NCH=20) — round-2
// exact. A: per (b,c) zero-seeded chunk-final EMA F. B: carry prefix S.
// C: seeded re-run + softmax accumulation (4-t batched shfl). D: reduce.
// ---------------------------------------------------------------------------
__global__ __launch_bounds__(64) void scanA_kernel(
        const unsigned short* __restrict__ Wx, const float* __restrict__ alpha,
        float* __restrict__ F) {
    const int c = blockIdx.x, b = blockIdx.y;
    const int lane = threadIdx.x;
    const int h = lane * 4;

    const float AMIN = 0.81873075307798182f, AMAX = 0.96078943915232320f;
    float4 al = *(const float4*)(alpha + h);
    float a[4]  = {fminf(fmaxf(al.x, AMIN), AMAX), fminf(fmaxf(al.y, AMIN), AMAX),
                   fminf(fmaxf(al.z, AMIN), AMAX), fminf(fmaxf(al.w, AMIN), AMAX)};
    float om[4] = {1.f - a[0], 1.f - a[1], 1.f - a[2], 1.f - a[3]};

    float ut[4] = {0.f, 0.f, 0.f, 0.f};
    const unsigned short* base = Wx + ((size_t)b * T_ + c * CHUNK) * H_ + h;
#pragma unroll 5
    for (int t = 0; t < CHUNK; ++t) {
        ull wv = *(const ull*)(base + (size_t)t * H_);
        ut[0] = a[0] * ut[0] + om[0] * bf2f((unsigned short)wv);
        ut[1] = a[1] * ut[1] + om[1] * bf2f((unsigned short)(wv >> 16));
        ut[2] = a[2] * ut[2] + om[2] * bf2f((unsigned short)(wv >> 32));
        ut[3] = a[3] * ut[3] + om[3] * bf2f((unsigned short)(wv >> 48));
    }
    float4 o; o.x = ut[0]; o.y = ut[1]; o.z = ut[2]; o.w = ut[3];
    *(float4*)(F + ((size_t)b * NCH + c) * H_ + h) = o;
}

__global__ __launch_bounds__(256) void scanB_kernel(
        const float* __restrict__ F, const float* __restrict__ alpha,
        float* __restrict__ S) {
    const int b = blockIdx.x, h = threadIdx.x;
    const float AMIN = 0.81873075307798182f, AMAX = 0.96078943915232320f;
    const float a = fminf(fmaxf(alpha[h], AMIN), AMAX);
    const float aL = powf(a, (float)CHUNK);
    float s = 0.f;
    for (int c = 0; c < NCH; ++c) {
        S[((size_t)b * NCH + c) * H_ + h] = s;
        s = aL * s + F[((size_t)b * NCH + c) * H_ + h];
    }
}

__global__ __launch_bounds__(64) void scanC_kernel(
        const unsigned short* __restrict__ Wx, const float* __restrict__ alpha,
        const float* __restrict__ S, float* __restrict__ P) {
    const int c = blockIdx.x + CSKIP;     // 2..19
    const int b = blockIdx.y;
    const int lane = threadIdx.x;
    const int h = lane * 4;

    const float AMIN = 0.81873075307798182f, AMAX = 0.96078943915232320f;
    float4 al = *(const float4*)(alpha + h);
    float a[4]  = {fminf(fmaxf(al.x, AMIN), AMAX), fminf(fmaxf(al.y, AMIN), AMAX),
                   fminf(fmaxf(al.z, AMIN), AMAX), fminf(fmaxf(al.w, AMIN), AMAX)};
    float om[4] = {1.f - a[0], 1.f - a[1], 1.f - a[2], 1.f - a[3]};

    float4 s0 = *(const float4*)(S + ((size_t)b * NCH + c) * H_ + h);
    float ut[4]   = {s0.x, s0.y, s0.z, s0.w};
    float acc4[4] = {0.f, 0.f, 0.f, 0.f};

    const unsigned short* base = Wx + ((size_t)b * T_ + c * CHUNK) * H_ + h;
#pragma unroll
    for (int tb = 0; tb < CHUNK; tb += 5) {
        float e[5][4], sl[5];
#pragma unroll
        for (int q = 0; q < 5; ++q) {
            ull wv = *(const ull*)(base + (size_t)(tb + q) * H_);
            ut[0] = a[0] * ut[0] + om[0] * bf2f((unsigned short)wv);
            ut[1] = a[1] * ut[1] + om[1] * bf2f((unsigned short)(wv >> 16));
            ut[2] = a[2] * ut[2] + om[2] * bf2f((unsigned short)(wv >> 32));
            ut[3] = a[3] * ut[3] + om[3] * bf2f((unsigned short)(wv >> 48));
            e[q][0] = __expf(ut[0]);   // |ut| small: overflow impossible
            e[q][1] = __expf(ut[1]);
            e[q][2] = __expf(ut[2]);
            e[q][3] = __expf(ut[3]);
            sl[q] = (e[q][0] + e[q][1]) + (e[q][2] + e[q][3]);
        }
#pragma unroll
        for (int dd = 1; dd < 64; dd <<= 1) {
            sl[0] += __shfl_xor(sl[0], dd);
            sl[1] += __shfl_xor(sl[1], dd);
            sl[2] += __shfl_xor(sl[2], dd);
            sl[3] += __shfl_xor(sl[3], dd);
            sl[4] += __shfl_xor(sl[4], dd);
        }
#pragma unroll
        for (int q = 0; q < 5; ++q) {
            const float rcp = 1.0f / sl[q];
            acc4[0] += e[q][0] * rcp;
            acc4[1] += e[q][1] * rcp;
            acc4[2] += e[q][2] * rcp;
            acc4[3] += e[q][3] * rcp;
        }
    }
    float4 o; o.x = acc4[0]; o.y = acc4[1]; o.z = acc4[2]; o.w = acc4[3];
    *(float4*)(P + ((size_t)b * NCH + c) * H_ + h) = o;
}

__global__ __launch_bounds__(256) void scanD_kernel(
        const float* __restrict__ P, float* __restrict__ out) {
    const int b = blockIdx.x, h = threadIdx.x;
    float s = 0.f;
    for (int c = CSKIP; c < NCH; ++c) s += P[((size_t)b * NCH + c) * H_ + h];
    out[(size_t)b * H_ + h] = s;
}

extern "C" void kernel_launch(void* const* d_in, const int* in_sizes, int n_in,
                              void* d_out, int out_size, void* d_ws, size_t ws_size,
                              hipStream_t stream) {
    const float* x     = (const float*)d_in[0];   // [B,T,D]
    const float* W     = (const float*)d_in[1];   // [H,D]
    const float* alpha = (const float*)d_in[2];   // [H]
    float* out = (float*)d_out;                   // [B,H]

    char* ws = (char*)d_ws;
    unsigned short* Wbf = (unsigned short*)ws;                        // 512 KB
    unsigned short* Wx  = (unsigned short*)(ws + ((size_t)1 << 20));  // 65.5 MB
    float* F = (float*)(ws + ((size_t)70 << 20));                     // 2.62 MB
    float* S = (float*)(ws + ((size_t)80 << 20));                     // 2.62 MB
    float* P = (float*)(ws + ((size_t)90 << 20));                     // 2.62 MB

    wconv_kernel<<<128, 256, 0, stream>>>(W, Wbf);
    gemm_kernel<<<(B_ * T_) / 128, 512, 0, stream>>>(x, Wbf, Wx);
    scanA_kernel<<<dim3(NCH, B_), 64, 0, stream>>>(Wx, alpha, F);
    scanB_kernel<<<B_, H_, 0, stream>>>(F, alpha, S);
    scanC_kernel<<<dim3(NCH - CSKIP, B_), 64, 0, stream>>>(Wx, alpha, S, P);
    scanD_kernel<<<B_, 256, 0, stream>>>(P, out);
}

// Round 10
// 174.010 us; speedup vs baseline: 1.1817x; 1.0250x over previous
//
#include <hip/hip_runtime.h>
#include <hip/hip_bf16.h>

#define B_    128
#define T_    1000
#define D_    1024
#define H_    256
#define TCROP 100
#define CHUNK 50
#define NCH   20            // T_/CHUNK
#define CSKIP 2             // TCROP/CHUNK (exact)

typedef __attribute__((ext_vector_type(8))) short bfrag8;   // 8 x bf16
typedef __attribute__((ext_vector_type(4))) float f32x4;
typedef unsigned long long ull;

__device__ __forceinline__ unsigned short f2bf(float f) {
    union { float f; unsigned int u; } v; v.f = f;
    unsigned int u = v.u;
    u += 0x7FFFu + ((u >> 16) & 1u);   // RNE
    return (unsigned short)(u >> 16);
}
__device__ __forceinline__ float bf2f(unsigned short u) {
    union { unsigned int u; float f; } v; v.u = ((unsigned int)u) << 16;
    return v.f;
}
// pack two f32 -> (bf16(hi)<<16)|bf16(lo), round-half-away: 2 adds + 1 v_perm
__device__ __forceinline__ unsigned int pack2(float lo, float hi) {
    union { float f; unsigned int u; } a, b; a.f = lo; b.f = hi;
    return __builtin_amdgcn_perm(b.u + 0x8000u, a.u + 0x8000u, 0x07060302u);
}
__device__ __forceinline__ bfrag8 cvt8(float4 f0, float4 f1) {
    union { bfrag8 v; unsigned int u[4]; } r;
    r.u[0] = pack2(f0.x, f0.y);
    r.u[1] = pack2(f0.z, f0.w);
    r.u[2] = pack2(f1.x, f1.y);
    r.u[3] = pack2(f1.z, f1.w);
    return r.v;
}

// ---------------------------------------------------------------------------
// Kernel 0: W f32 [H][D] -> bf16 (row-major)
// ---------------------------------------------------------------------------
__global__ __launch_bounds__(256) void wconv_kernel(
        const float* __restrict__ W, unsigned short* __restrict__ Wbf) {
    const int i = (blockIdx.x * 256 + threadIdx.x) * 8;
    float4 f0 = *(const float4*)(W + i);
    float4 f1 = *(const float4*)(W + i + 4);
    *(bfrag8*)(Wbf + i) = cvt8(f0, f1);
}

// ---------------------------------------------------------------------------
// Kernel 1: Wx = x(bf16) . W^T. BM=128, BN=256(=H), BK=64. Champion r2/r9
// K-loop (single-buffer, 2 barriers/K-step, B gload_lds first, A reg+cvt).
// NEW: epilogue rounds acc through a 64KB LDS C-tile (staging LDS is dead
// after the K-loop) and stores Wx fully coalesced (1KB/wave b128 runs)
// instead of scattered 2B stores -> kills store write-amplification.
// ---------------------------------------------------------------------------
__global__ __launch_bounds__(512) void gemm_kernel(
        const float* __restrict__ x, const unsigned short* __restrict__ Wbf,
        unsigned short* __restrict__ Wx) {
    __shared__ unsigned short smem[32768];    // 64 KB
    unsigned short* As = smem;                // [128][64] bf16 (16 KB)
    unsigned short* Bs = smem + 128 * 64;     // [256][64] bf16 (32 KB)

    const int tid  = threadIdx.x;
    const int lane = tid & 63;
    const int wave = tid >> 6;
    const int wr   = wave >> 2;          // 0..1
    const int wc   = wave & 3;           // 0..3
    const int m0   = blockIdx.x * 128;

    f32x4 acc[4][4];
#pragma unroll
    for (int m = 0; m < 4; ++m)
#pragma unroll
        for (int n = 0; n < 4; ++n) acc[m][n] = (f32x4){0.f, 0.f, 0.f, 0.f};

    const int rr  = lane & 15;
    const int kh  = lane >> 4;           // 0..3
    const int ra0 = tid >> 3;            // A-stage row (and +64)
    const int ja  = tid & 7;             // A-stage chunk
    const int sa  = (ja ^ (ra0 & 7)) * 8;

    for (int kt = 0; kt < D_; kt += 64) {
        // ---- B stage: 4x global_load_lds, 16B/lane, source pre-swizzled ----
#pragma unroll
        for (int q = 0; q < 4; ++q) {
            const int li = q * 512 + tid;        // 0..2047
            const int r  = li >> 3;
            const int j  = li & 7;
            const int jj = j ^ (r & 7);
            const unsigned short* src = Wbf + (size_t)r * D_ + kt + jj * 8;
            unsigned short* dst = &Bs[li * 8];
            __builtin_amdgcn_global_load_lds(
                (const __attribute__((address_space(1))) void*)src,
                (__attribute__((address_space(3))) void*)dst, 16, 0, 0);
        }
        // ---- A stage: reg path, f32->bf16, write-side swizzle ----
#pragma unroll
        for (int q = 0; q < 2; ++q) {
            const int r = ra0 + q * 64;
            const float* src = x + (size_t)(m0 + r) * D_ + kt + ja * 8;
            float4 f0 = *(const float4*)src;
            float4 f1 = *(const float4*)(src + 4);
            *(bfrag8*)&As[r * 64 + sa] = cvt8(f0, f1);
        }
        __syncthreads();

        // ---- fragments + MFMA ----
#pragma unroll
        for (int kk = 0; kk < 2; ++kk) {
            const int c16 = kk * 4 + kh;
            bfrag8 af[4], bfr[4];
#pragma unroll
            for (int m = 0; m < 4; ++m) {
                const int row = wr * 64 + m * 16 + rr;
                af[m] = *(const bfrag8*)&As[row * 64 + ((c16 ^ (row & 7)) * 8)];
            }
#pragma unroll
            for (int n = 0; n < 4; ++n) {
                const int row = wc * 64 + n * 16 + rr;
                bfr[n] = *(const bfrag8*)&Bs[row * 64 + ((c16 ^ (row & 7)) * 8)];
            }
#pragma unroll
            for (int m = 0; m < 4; ++m)
#pragma unroll
                for (int n = 0; n < 4; ++n)
                    acc[m][n] = __builtin_amdgcn_mfma_f32_16x16x32_bf16(
                        af[m], bfr[n], acc[m][n], 0, 0, 0);
        }
        __syncthreads();
    }

    // ---- epilogue: acc -> LDS C-tile [128][256] bf16 (col-XOR swizzle),
    //      then coalesced b128 stores ----
    const int cl = lane & 15, rg = lane >> 4;
#pragma unroll
    for (int m = 0; m < 4; ++m)
#pragma unroll
        for (int n = 0; n < 4; ++n)
#pragma unroll
            for (int j = 0; j < 4; ++j) {
                const int row = wr * 64 + m * 16 + rg * 4 + j;
                const int col = wc * 64 + n * 16 + cl;
                smem[row * 256 + (col ^ (((row >> 2) & 3) << 4))] =
                    f2bf(acc[m][n][j]);
            }
    __syncthreads();
#pragma unroll
    for (int li = tid; li < 4096; li += 512) {
        const int r  = li >> 5;                    // 0..127
        const int cg = (li & 31) * 8;              // granule base col
        const int scg = cg ^ (((r >> 2) & 3) << 4);
        bfrag8 v = *(const bfrag8*)&smem[r * 256 + scg];
        *(bfrag8*)&Wx[(size_t)(m0 + r) * H_ + cg] = v;
    }
}

// ---------------------------------------------------------------------------
// Kernel 2 (scanA): per (b,c) zero-seeded chunk-final EMA F.
// 10-deep unroll: 80B/lane of loads in flight (latency fill at 10 waves/CU).
// ---------------------------------------------------------------------------
__global__ __launch_bounds__(64) void scanA_kernel(
        const unsigned short* __restrict__ Wx, const float* __restrict__ alpha,
        float* __restrict__ F) {
    const int c = blockIdx.x, b = blockIdx.y;
    const int lane = threadIdx.x;
    const int h = lane * 4;

    const float AMIN = 0.81873075307798182f, AMAX = 0.96078943915232320f;
    float4 al = *(const float4*)(alpha + h);
    float a[4]  = {fminf(fmaxf(al.x, AMIN), AMAX), fminf(fmaxf(al.y, AMIN), AMAX),
                   fminf(fmaxf(al.z, AMIN), AMAX), fminf(fmaxf(al.w, AMIN), AMAX)};
    float om[4] = {1.f - a[0], 1.f - a[1], 1.f - a[2], 1.f - a[3]};

    float ut[4] = {0.f, 0.f, 0.f, 0.f};
    const unsigned short* base = Wx + ((size_t)b * T_ + c * CHUNK) * H_ + h;
#pragma unroll 10
    for (int t = 0; t < CHUNK; ++t) {
        ull wv = *(const ull*)(base + (size_t)t * H_);
        ut[0] = a[0] * ut[0] + om[0] * bf2f((unsigned short)wv);
        ut[1] = a[1] * ut[1] + om[1] * bf2f((unsigned short)(wv >> 16));
        ut[2] = a[2] * ut[2] + om[2] * bf2f((unsigned short)(wv >> 32));
        ut[3] = a[3] * ut[3] + om[3] * bf2f((unsigned short)(wv >> 48));
    }
    float4 o; o.x = ut[0]; o.y = ut[1]; o.z = ut[2]; o.w = ut[3];
    *(float4*)(F + ((size_t)b * NCH + c) * H_ + h) = o;
}

// ---------------------------------------------------------------------------
// Kernel 3 (scanB): carry prefix S over chunks. Fully unrolled so the
// 20 F-loads hoist instead of forming a dependent load-FMA chain.
// ---------------------------------------------------------------------------
__global__ __launch_bounds__(256) void scanB_kernel(
        const float* __restrict__ F, const float* __restrict__ alpha,
        float* __restrict__ S) {
    const int b = blockIdx.x, h = threadIdx.x;
    const float AMIN = 0.81873075307798182f, AMAX = 0.96078943915232320f;
    const float a = fminf(fmaxf(alpha[h], AMIN), AMAX);
    const float aL = powf(a, (float)CHUNK);
    float f[NCH];
#pragma unroll
    for (int c = 0; c < NCH; ++c)
        f[c] = F[((size_t)b * NCH + c) * H_ + h];
    float s = 0.f;
#pragma unroll
    for (int c = 0; c < NCH; ++c) {
        S[((size_t)b * NCH + c) * H_ + h] = s;
        s = aL * s + f[c];
    }
}

// ---------------------------------------------------------------------------
// Kernel 4 (scanC): seeded re-run + softmax accumulation (5-t batched shfl).
// ---------------------------------------------------------------------------
__global__ __launch_bounds__(64) void scanC_kernel(
        const unsigned short* __restrict__ Wx, const float* __restrict__ alpha,
        const float* __restrict__ S, float* __restrict__ P) {
    const int c = blockIdx.x + CSKIP;     // 2..19
    const int b = blockIdx.y;
    const int lane = threadIdx.x;
    const int h = lane * 4;

    const float AMIN = 0.81873075307798182f, AMAX = 0.96078943915232320f;
    float4 al = *(const float4*)(alpha + h);
    float a[4]  = {fminf(fmaxf(al.x, AMIN), AMAX), fminf(fmaxf(al.y, AMIN), AMAX),
                   fminf(fmaxf(al.z, AMIN), AMAX), fminf(fmaxf(al.w, AMIN), AMAX)};
    float om[4] = {1.f - a[0], 1.f - a[1], 1.f - a[2], 1.f - a[3]};

    float4 s0 = *(const float4*)(S + ((size_t)b * NCH + c) * H_ + h);
    float ut[4]   = {s0.x, s0.y, s0.z, s0.w};
    float acc4[4] = {0.f, 0.f, 0.f, 0.f};

    const unsigned short* base = Wx + ((size_t)b * T_ + c * CHUNK) * H_ + h;
#pragma unroll
    for (int tb = 0; tb < CHUNK; tb += 5) {
        float e[5][4], sl[5];
#pragma unroll
        for (int q = 0; q < 5; ++q) {
            ull wv = *(const ull*)(base + (size_t)(tb + q) * H_);
            ut[0] = a[0] * ut[0] + om[0] * bf2f((unsigned short)wv);
            ut[1] = a[1] * ut[1] + om[1] * bf2f((unsigned short)(wv >> 16));
            ut[2] = a[2] * ut[2] + om[2] * bf2f((unsigned short)(wv >> 32));
            ut[3] = a[3] * ut[3] + om[3] * bf2f((unsigned short)(wv >> 48));
            e[q][0] = __expf(ut[0]);   // |ut| small: overflow impossible
            e[q][1] = __expf(ut[1]);
            e[q][2] = __expf(ut[2]);
            e[q][3] = __expf(ut[3]);
            sl[q] = (e[q][0] + e[q][1]) + (e[q][2] + e[q][3]);
        }
#pragma unroll
        for (int dd = 1; dd < 64; dd <<= 1) {
            sl[0] += __shfl_xor(sl[0], dd);
            sl[1] += __shfl_xor(sl[1], dd);
            sl[2] += __shfl_xor(sl[2], dd);
            sl[3] += __shfl_xor(sl[3], dd);
            sl[4] += __shfl_xor(sl[4], dd);
        }
#pragma unroll
        for (int q = 0; q < 5; ++q) {
            const float rcp = 1.0f / sl[q];
            acc4[0] += e[q][0] * rcp;
            acc4[1] += e[q][1] * rcp;
            acc4[2] += e[q][2] * rcp;
            acc4[3] += e[q][3] * rcp;
        }
    }
    float4 o; o.x = acc4[0]; o.y = acc4[1]; o.z = acc4[2]; o.w = acc4[3];
    *(float4*)(P + ((size_t)b * NCH + c) * H_ + h) = o;
}

__global__ __launch_bounds__(256) void scanD_kernel(
        const float* __restrict__ P, float* __restrict__ out) {
    const int b = blockIdx.x, h = threadIdx.x;
    float s = 0.f;
    for (int c = CSKIP; c < NCH; ++c) s += P[((size_t)b * NCH + c) * H_ + h];
    out[(size_t)b * H_ + h] = s;
}

extern "C" void kernel_launch(void* const* d_in, const int* in_sizes, int n_in,
                              void* d_out, int out_size, void* d_ws, size_t ws_size,
                              hipStream_t stream) {
    const float* x     = (const float*)d_in[0];   // [B,T,D]
    const float* W     = (const float*)d_in[1];   // [H,D]
    const float* alpha = (const float*)d_in[2];   // [H]
    float* out = (float*)d_out;                   // [B,H]

    char* ws = (char*)d_ws;
    unsigned short* Wbf = (unsigned short*)ws;                        // 512 KB
    unsigned short* Wx  = (unsigned short*)(ws + ((size_t)1 << 20));  // 65.5 MB
    float* F = (float*)(ws + ((size_t)70 << 20));                     // 2.62 MB
    float* S = (float*)(ws + ((size_t)80 << 20));                     // 2.62 MB
    float* P = (float*)(ws + ((size_t)90 << 20));                     // 2.62 MB

    wconv_kernel<<<128, 256, 0, stream>>>(W, Wbf);
    gemm_kernel<<<(B_ * T_) / 128, 512, 0, stream>>>(x, Wbf, Wx);
    scanA_kernel<<<dim3(NCH, B_), 64, 0, stream>>>(Wx, alpha, F);
    scanB_kernel<<<B_, H_, 0, stream>>>(F, alpha, S);
    scanC_kernel<<<dim3(NCH - CSKIP, B_), 64, 0, stream>>>(Wx, alpha, S, P);
    scanD_kernel<<<B_, 256, 0, stream>>>(P, out);
}